// Round 1
// baseline (1052.072 us; speedup 1.0000x reference)
//
#include <hip/hip_runtime.h>
#include <hip/hip_cooperative_groups.h>
#include <math.h>

namespace cg = cooperative_groups;

#define FD     512
#define NBATCH 16
#define NROWS  16384
#define ROWS   64              // rows per block
#define NBLK   (NROWS/ROWS)    // 256 blocks = 1 per CU (cooperative-resident)
#define TPB    1024            // 16 waves/block
#define MM     5
#define LAMV   1e-4f
#define MAXIT  50
#define TOLV   0.01f
#define NTOT   8388608
#define PADW   520             // LDS row stride (bf16 elems), 16B aligned

typedef __attribute__((ext_vector_type(8))) short  short8;   // 8 bf16
typedef __attribute__((ext_vector_type(4))) float  float4v;  // MFMA C/D frag

// Persistent device state; fully rewritten (or provably unused) every call.
__device__ unsigned short g_Fm[MM][NTOT];
__device__ unsigned short g_G [MM][NTOT];
__device__ unsigned short g_xb[NTOT];          // fallback path only
__device__ unsigned short g_Wb [FD*FD];        // bf16(lin_w) row-major
__device__ unsigned short g_WbO[FD*FD];        // bf16(weight) row-major
__device__ float g_acc [MAXIT-2][NBATCH][8];   // per-iter Gram-row dots [0..4], ||f||^2 [5]
__device__ float g_acc0[NBATCH][8];            // init dots d00,d01,d11

static __device__ __forceinline__ unsigned short f2bf(float f) {
    unsigned u = __float_as_uint(f);
    u += 0x7fff + ((u >> 16) & 1);             // RNE
    return (unsigned short)(u >> 16);
}
static __device__ __forceinline__ float bf2f(unsigned short s) {
    return __uint_as_float(((unsigned)s) << 16);
}

// 64x512 tile GEMM: D = A(64x512 bf16, LDS) @ W^T + bias.
// 16 waves; wave owns 32 output cols (2 ct) x all 64 rows (4 r16) -> each B
// fragment feeds 4 MFMAs (4:1 reuse), halving L2 B-traffic vs 32-row blocks.
// MODE 0: bf16 -> FsOut (LDS). MODE 1: fp32 -> gout (global tile base).
template<int MODE>
static __device__ __forceinline__ void mfma_gemm(const unsigned short* __restrict__ Wb,
                                                 const float* __restrict__ bvec,
                                                 const unsigned short* AsIn,
                                                 unsigned short* FsOut,
                                                 float* __restrict__ gout)
{
    const int lane = threadIdx.x & 63;
    const int wv   = threadIdx.x >> 6;     // 0..15
    const int lm   = lane & 15;
    const int quad = lane >> 4;
    float4v acc[4][2];
#pragma unroll
    for (int ct = 0; ct < 2; ct++) {
        const float b = bvec[wv*32 + ct*16 + lm];
#pragma unroll
        for (int r16 = 0; r16 < 4; r16++) {
            acc[r16][ct][0]=b; acc[r16][ct][1]=b; acc[r16][ct][2]=b; acc[r16][ct][3]=b;
        }
    }
#pragma unroll
    for (int q = 0; q < 4; q++) {
#pragma unroll
        for (int kb = 0; kb < 4; kb++) {
            const int ko = q*128 + kb*32 + quad*8;
            short8 bf[2];
#pragma unroll
            for (int ct = 0; ct < 2; ct++)
                bf[ct] = *(const short8*)(Wb + (wv*32 + ct*16 + lm)*FD + ko);
            short8 af[4];
#pragma unroll
            for (int r16 = 0; r16 < 4; r16++)
                af[r16] = *(const short8*)(AsIn + (r16*16 + lm)*PADW + ko);
#pragma unroll
            for (int r16 = 0; r16 < 4; r16++) {
                acc[r16][0] = __builtin_amdgcn_mfma_f32_16x16x32_bf16(af[r16], bf[0], acc[r16][0], 0,0,0);
                acc[r16][1] = __builtin_amdgcn_mfma_f32_16x16x32_bf16(af[r16], bf[1], acc[r16][1], 0,0,0);
            }
        }
    }
#pragma unroll
    for (int ct = 0; ct < 2; ct++) {
        const int c = wv*32 + ct*16 + lm;
#pragma unroll
        for (int r16 = 0; r16 < 4; r16++)
#pragma unroll
            for (int r = 0; r < 4; r++) {
                const int row = r16*16 + quad*4 + r;
                if (MODE == 0) FsOut[row*PADW + c] = f2bf(acc[r16][ct][r]);
                else           gout[row*FD + c]    = acc[r16][ct][r];
            }
    }
}

static __device__ __forceinline__ void red6(const float vals[6], float (*redS)[8], float* accrow)
{
    const int lane = threadIdx.x & 63, wv = threadIdx.x >> 6;   // wv 0..15
#pragma unroll
    for (int j = 0; j < 6; j++) {
        float v = vals[j];
#pragma unroll
        for (int o = 32; o; o >>= 1) v += __shfl_down(v, o);
        if (lane == 0) redS[wv][j] = v;
    }
    __syncthreads();
    if (threadIdx.x < 6) {
        float s = 0.f;
#pragma unroll
        for (int w = 0; w < 16; w++) s += redS[w][threadIdx.x];
        atomicAdd(accrow + threadIdx.x, s);   // device-scope
    }
}

// ======================= persistent cooperative kernel =======================
// Whole Anderson solve in ONE dispatch: phase0 (weights->bf16, zero accs,
// x->LDS) / init (F0,F1,G0,G1 + init dots) / k-loop with one grid.sync per
// iteration + uniform early break / final GEMM from the As tile still in LDS.
// Cross-block traffic is ONLY g_acc (atomicAdd, ordered by grid.sync).
__global__ void __launch_bounds__(TPB, 4) k_anderson(
    const float* __restrict__ x,     const float* __restrict__ lin_w,
    const float* __restrict__ lin_b, const float* __restrict__ weight,
    const float* __restrict__ bias,  float* __restrict__ out)
{
    cg::grid_group grid = cg::this_grid();

    __shared__ __align__(16) unsigned short As[ROWS*PADW];
    __shared__ __align__(16) unsigned short Fs[ROWS*PADW];
    __shared__ float redS[16][8];
    __shared__ float gramS[MM][MM];
    __shared__ float alphaS[MM];
    __shared__ float Hs[48];
    __shared__ float gAs[MM][MM];   // Gram window cache (wave-1 parallel load)
    __shared__ float ga0S[3];       // d00,d01,d11
    __shared__ float sres;

    const int tid  = threadIdx.x;
    const int t    = blockIdx.x, b = t >> 4;
    const int base = t * (ROWS*FD);

    // ---------- phase 0: weights -> bf16, zero accumulators, x -> As ----------
    {
        const int gi = t*TPB + tid;            // grid has exactly FD*FD threads
        g_Wb [gi] = f2bf(lin_w[gi]);
        g_WbO[gi] = f2bf(weight[gi]);
        if (gi < (MAXIT-2)*NBATCH*8) (&g_acc[0][0][0])[gi] = 0.f;
        if (gi < NBATCH*8)           (&g_acc0[0][0])[gi]   = 0.f;
    }
#pragma unroll
    for (int i = 0; i < 4; i++) {               // bf16(x0 tile) -> As
        const int e = (i*TPB + tid) * 8;
        const float4 a0 = *(const float4*)(x + base + e);
        const float4 a1 = *(const float4*)(x + base + e + 4);
        short8 v;
        v[0]=f2bf(a0.x); v[1]=f2bf(a0.y); v[2]=f2bf(a0.z); v[3]=f2bf(a0.w);
        v[4]=f2bf(a1.x); v[5]=f2bf(a1.y); v[6]=f2bf(a1.z); v[7]=f2bf(a1.w);
        *(short8*)(As + (e>>9)*PADW + (e&511)) = v;
    }
    grid.sync();                                // g_Wb/g_acc ready device-wide

    // ---------- init: F0=f(x~0), F1=f(F~0), G0, G1, init Gram dots ------------
    mfma_gemm<0>(g_Wb, lin_b, As, Fs, nullptr);   // Fs = bf16(f(x~0))
    __syncthreads();
    float d00 = 0.f;
#pragma unroll
    for (int i = 0; i < 4; i++) {
        const int e = (i*TPB + tid) * 8;
        const int off = base + e, lo = (e>>9)*PADW + (e&511);
        const short8 fv = *(const short8*)(Fs + lo);
        const short8 xv = *(const short8*)(As + lo);
        short8 gv;
#pragma unroll
        for (int j = 0; j < 8; j++) {
            const float g = bf2f((unsigned short)fv[j]) - bf2f((unsigned short)xv[j]);
            gv[j] = (short)f2bf(g);
            d00 = fmaf(g, g, d00);
        }
        *(short8*)(&g_Fm[0][off]) = fv;
        *(short8*)(&g_G [0][off]) = gv;
    }
    __syncthreads();
    mfma_gemm<0>(g_Wb, lin_b, Fs, As, nullptr);   // As = bf16(f(F~0))
    __syncthreads();
    float d01 = 0.f, d11 = 0.f;
#pragma unroll
    for (int i = 0; i < 4; i++) {
        const int e = (i*TPB + tid) * 8;
        const int off = base + e, lo = (e>>9)*PADW + (e&511);
        const short8 f1 = *(const short8*)(As + lo);
        const short8 f0 = *(const short8*)(Fs + lo);
        const short8 g0 = *(const short8*)(&g_G[0][off]);
        short8 gv;
#pragma unroll
        for (int j = 0; j < 8; j++) {
            const float g = bf2f((unsigned short)f1[j]) - bf2f((unsigned short)f0[j]);
            gv[j] = (short)f2bf(g);
            d11 = fmaf(g, g, d11);
            d01 = fmaf(bf2f((unsigned short)g0[j]), g, d01);
        }
        *(short8*)(&g_Fm[1][off]) = f1;
        *(short8*)(&g_G [1][off]) = gv;
    }
    {
        const float vals[6] = {d00, d01, d11, 0.f, 0.f, 0.f};
        red6(vals, redS, &g_acc0[b][0]);
    }
    grid.sync();                                // init dots visible device-wide

    // ---------------- Anderson iterations (k = 2..49) -------------------------
    for (int k = 2; k < MAXIT; k++) {
        const int it = k - 2, idx = k % MM, nk = (k < MM) ? k : MM;
        const int j0 = (k - 5 > 2) ? (k - 5) : 2;

        // wave 0: residual of iteration k-1 (global across batches)
        if (k > 2 && (tid >> 6) == 0) {
            float v = 0.f;
            if (tid < 32) {
                const int bb = tid & 15;
                const int jj = (tid < 16) ? ((k-1) % MM) : 5;
                v = g_acc[it-1][bb][jj];
            }
            v += __shfl_xor(v, 1); v += __shfl_xor(v, 2);
            v += __shfl_xor(v, 4); v += __shfl_xor(v, 8);
            const float num = __shfl(v, 0), den = __shfl(v, 16);
            if (tid == 0) sres = sqrtf(num) / (1e-5f + sqrtf(den));
        }
        // wave 1: Gram window + init dots -> LDS (kills ~25 serialized lane-0
        // global loads; values identical to the previous serial replay source)
        if ((tid >> 6) == 1) {
            const int l = tid & 63;
            if (l < 25) {
                const int jj = j0 + l/5;
                if (jj < k) gAs[l/5][l%5] = g_acc[jj-2][b][l%5];
            } else if (l < 28) {
                ga0S[l-25] = g_acc0[b][l-25];
            }
        }
        __syncthreads();
        if (k > 2 && sres < TOLV) break;        // uniform across grid

        // --- Gram replay (chronological, last <=5 iterations) + bordered solve
        if (tid == 0) {
#pragma unroll
            for (int i = 0; i < MM; i++)
#pragma unroll
                for (int j = 0; j < MM; j++) gramS[i][j] = 0.f;
            gramS[0][0] = ga0S[0];
            gramS[0][1] = gramS[1][0] = ga0S[1];
            gramS[1][1] = ga0S[2];
            for (int j = j0; j < k; j++) {
                const int ij = j % MM, nkj = (j < MM) ? j : MM;
                for (int c = 0; c < MM; c++)
                    if (c < nkj || c == ij) {
                        const float vv = gAs[j - j0][c];
                        gramS[ij][c] = vv; gramS[c][ij] = vv;
                    }
            }
            float* H = Hs;                      // 6x7 augmented
            for (int i = 0; i < 42; i++) H[i] = 0.f;
            for (int j = 0; j < nk; j++) { H[1+j] = 1.f; H[(1+j)*7] = 1.f; }
#pragma unroll
            for (int i = 0; i < MM; i++) H[(1+i)*7 + (1+i)] = LAMV;
            for (int i = 0; i < nk; i++)
                for (int j = 0; j < nk; j++)
                    H[(1+i)*7 + (1+j)] = gramS[i][j] + (i == j ? LAMV : 0.f);
            H[6] = 1.f;                         // rhs = e0
            for (int col = 0; col < 6; col++) {
                int p = col; float mx = fabsf(H[col*7+col]);
                for (int r2 = col+1; r2 < 6; r2++) {
                    const float vv = fabsf(H[r2*7+col]);
                    if (vv > mx) { mx = vv; p = r2; }
                }
                if (p != col)
                    for (int j = col; j < 7; j++) { const float tt = H[col*7+j]; H[col*7+j] = H[p*7+j]; H[p*7+j] = tt; }
                const float piv = H[col*7+col];
                for (int r2 = col+1; r2 < 6; r2++) {
                    const float fct = H[r2*7+col] / piv;
                    for (int j = col+1; j < 7; j++) H[r2*7+j] -= fct * H[col*7+j];
                }
            }
            for (int r2 = 5; r2 >= 0; r2--) {
                float s = H[r2*7+6];
                for (int j = r2+1; j < 6; j++) s -= H[r2*7+j] * H[j*7+6];
                H[r2*7+6] = s / H[r2*7+r2];
            }
#pragma unroll
            for (int m = 0; m < MM; m++) alphaS[m] = H[(1+m)*7+6];
        }
        __syncthreads();

        float al[MM];
#pragma unroll
        for (int m = 0; m < MM; m++) al[m] = alphaS[m];

        // --- pass 1: x~ = bf16(sum_m alpha_m Fm[m]) -> As (LDS only; no g_xb)
        if (nk == MM) {
#pragma unroll
            for (int i = 0; i < 4; i++) {
                const int e = (i*TPB + tid) * 8;
                const int off = base + e;
                float s[8] = {0,0,0,0,0,0,0,0};
#pragma unroll
                for (int m = 0; m < MM; m++) {
                    const short8 fm = *(const short8*)(&g_Fm[m][off]);
#pragma unroll
                    for (int j = 0; j < 8; j++)
                        s[j] = fmaf(al[m], bf2f((unsigned short)fm[j]), s[j]);
                }
                short8 v;
#pragma unroll
                for (int j = 0; j < 8; j++) v[j] = (short)f2bf(s[j]);
                *(short8*)(As + (e>>9)*PADW + (e&511)) = v;
            }
        } else {
#pragma unroll
            for (int i = 0; i < 4; i++) {
                const int e = (i*TPB + tid) * 8;
                const int off = base + e;
                float s[8] = {0,0,0,0,0,0,0,0};
                for (int m = 0; m < nk; m++) {
                    const short8 fm = *(const short8*)(&g_Fm[m][off]);
#pragma unroll
                    for (int j = 0; j < 8; j++)
                        s[j] = fmaf(al[m], bf2f((unsigned short)fm[j]), s[j]);
                }
                short8 v;
#pragma unroll
                for (int j = 0; j < 8; j++) v[j] = (short)f2bf(s[j]);
                *(short8*)(As + (e>>9)*PADW + (e&511)) = v;
            }
        }
        __syncthreads();
        // --- pass 2: Fs = bf16(x~ @ lin_w^T + lin_b)
        mfma_gemm<0>(g_Wb, lin_b, As, Fs, nullptr);
        __syncthreads();
        // --- pass 3: state writes + Gram-row dots + residual partials
        float dv[6] = {0,0,0,0,0,0};
        float dself = 0.f;
#pragma unroll
        for (int i = 0; i < 4; i++) {
            const int e = (i*TPB + tid) * 8;
            const int off = base + e, lo = (e>>9)*PADW + (e&511);
            const short8 fv = *(const short8*)(Fs + lo);
            const short8 xv = *(const short8*)(As + lo);
            float gg[8]; short8 gv;
#pragma unroll
            for (int j = 0; j < 8; j++) {
                const float ff = bf2f((unsigned short)fv[j]);
                const float g  = ff - bf2f((unsigned short)xv[j]);
                gg[j] = g; gv[j] = (short)f2bf(g);
                dv[5] = fmaf(ff, ff, dv[5]);
                dself = fmaf(g, g, dself);
            }
            *(short8*)(&g_Fm[idx][off]) = fv;
            *(short8*)(&g_G [idx][off]) = gv;
#pragma unroll
            for (int js = 0; js < MM; js++) {
                if (js != idx && js < nk) {
                    const short8 gj = *(const short8*)(&g_G[js][off]);
#pragma unroll
                    for (int j = 0; j < 8; j++)
                        dv[js] = fmaf(gg[j], bf2f((unsigned short)gj[j]), dv[js]);
                }
            }
        }
        float vals[6];
#pragma unroll
        for (int j = 0; j < MM; j++) vals[j] = (j == idx) ? (dv[j] + dself) : dv[j];
        vals[5] = dv[5];
        red6(vals, redS, &g_acc[it][b][0]);
        grid.sync();                            // g_acc[it] ready device-wide
    }

    // ---------------- final: out = x~last @ weight^T + bias (fp32) -----------
    // As (LDS) still holds bf16(xnew) of the last executed iteration: pass 2/3
    // only read it, and the break happens before any As write. Bit-identical
    // to the old g_xb round trip, minus 16.8 MB/iter of global traffic.
    mfma_gemm<1>(g_WbO, bias, As, nullptr, out + base);
}

// ===================== fallback multi-launch path (proven) ===================
__global__ void __launch_bounds__(256) k_init0(const float* __restrict__ lin_w,
                                               const float* __restrict__ weight)
{
    const int i0 = blockIdx.x*256 + threadIdx.x, stride = gridDim.x*256;
    for (int i = i0; i < FD*FD; i += stride) {
        g_Wb [i] = f2bf(lin_w[i]);
        g_WbO[i] = f2bf(weight[i]);
    }
    float* a = &g_acc[0][0][0];
    for (int i = i0; i < (MAXIT-2)*NBATCH*8; i += stride) a[i] = 0.f;
    float* a0 = &g_acc0[0][0];
    for (int i = i0; i < NBATCH*8; i += stride) a0[i] = 0.f;
}

__global__ void __launch_bounds__(TPB, 4) k_init1(const float* __restrict__ x,
                                                  const float* __restrict__ lin_b)
{
    __shared__ __align__(16) unsigned short As[ROWS*PADW];
    __shared__ __align__(16) unsigned short Fs[ROWS*PADW];
    __shared__ float redS[16][8];
    const int tid = threadIdx.x;
    const int t = blockIdx.x, b = t >> 4;
    const int base = t * (ROWS*FD);

#pragma unroll
    for (int i = 0; i < 4; i++) {
        const int e = (i*TPB + tid) * 8;
        const float4 a0 = *(const float4*)(x + base + e);
        const float4 a1 = *(const float4*)(x + base + e + 4);
        short8 v;
        v[0]=f2bf(a0.x); v[1]=f2bf(a0.y); v[2]=f2bf(a0.z); v[3]=f2bf(a0.w);
        v[4]=f2bf(a1.x); v[5]=f2bf(a1.y); v[6]=f2bf(a1.z); v[7]=f2bf(a1.w);
        *(short8*)(As + (e>>9)*PADW + (e&511)) = v;
    }
    __syncthreads();
    mfma_gemm<0>(g_Wb, lin_b, As, Fs, nullptr);
    __syncthreads();
    float d00 = 0.f;
#pragma unroll
    for (int i = 0; i < 4; i++) {
        const int e = (i*TPB + tid) * 8;
        const int off = base + e, lo = (e>>9)*PADW + (e&511);
        const short8 fv = *(const short8*)(Fs + lo);
        const short8 xv = *(const short8*)(As + lo);
        short8 gv;
#pragma unroll
        for (int j = 0; j < 8; j++) {
            const float g = bf2f((unsigned short)fv[j]) - bf2f((unsigned short)xv[j]);
            gv[j] = (short)f2bf(g);
            d00 = fmaf(g, g, d00);
        }
        *(short8*)(&g_Fm[0][off]) = fv;
        *(short8*)(&g_G [0][off]) = gv;
    }
    __syncthreads();
    mfma_gemm<0>(g_Wb, lin_b, Fs, As, nullptr);
    __syncthreads();
    float d01 = 0.f, d11 = 0.f;
#pragma unroll
    for (int i = 0; i < 4; i++) {
        const int e = (i*TPB + tid) * 8;
        const int off = base + e, lo = (e>>9)*PADW + (e&511);
        const short8 f1 = *(const short8*)(As + lo);
        const short8 f0 = *(const short8*)(Fs + lo);
        const short8 g0 = *(const short8*)(&g_G[0][off]);
        short8 gv;
#pragma unroll
        for (int j = 0; j < 8; j++) {
            const float g = bf2f((unsigned short)f1[j]) - bf2f((unsigned short)f0[j]);
            gv[j] = (short)f2bf(g);
            d11 = fmaf(g, g, d11);
            d01 = fmaf(bf2f((unsigned short)g0[j]), g, d01);
        }
        *(short8*)(&g_Fm[1][off]) = f1;
        *(short8*)(&g_G [1][off]) = gv;
    }
    const float vals[6] = {d00, d01, d11, 0.f, 0.f, 0.f};
    red6(vals, redS, &g_acc0[b][0]);
}

__global__ void __launch_bounds__(TPB, 4) k_iter(const float* __restrict__ lin_b, int k)
{
    __shared__ __align__(16) unsigned short As[ROWS*PADW];
    __shared__ __align__(16) unsigned short Fs[ROWS*PADW];
    __shared__ float gramS[MM][MM];
    __shared__ float alphaS[MM];
    __shared__ float Hs[48];
    __shared__ float redS[16][8];
    __shared__ float sres;

    const int tid = threadIdx.x;
    const int t = blockIdx.x, b = t >> 4;
    const int base = t * (ROWS*FD);
    const int it = k - 2, idx = k % MM, nk = (k < MM) ? k : MM;

    if (k > 2) {
        float v = 0.f;
        if (tid < 32) {
            const int bb = tid & 15;
            const int jj = (tid < 16) ? ((k-1) % MM) : 5;
            v = g_acc[it-1][bb][jj];
        }
        v += __shfl_xor(v, 1); v += __shfl_xor(v, 2);
        v += __shfl_xor(v, 4); v += __shfl_xor(v, 8);
        const float num = __shfl(v, 0), den = __shfl(v, 16);
        if (tid == 0) sres = sqrtf(num) / (1e-5f + sqrtf(den));
    }
    __syncthreads();
    if (k > 2 && sres < TOLV) return;

    if (tid == 0) {
#pragma unroll
        for (int i = 0; i < MM; i++)
#pragma unroll
            for (int j = 0; j < MM; j++) gramS[i][j] = 0.f;
        gramS[0][0] = g_acc0[b][0];
        gramS[0][1] = gramS[1][0] = g_acc0[b][1];
        gramS[1][1] = g_acc0[b][2];
        const int j0 = (k - 5 > 2) ? (k - 5) : 2;
        for (int j = j0; j < k; j++) {
            const int ij = j % MM, nkj = (j < MM) ? j : MM;
            for (int c = 0; c < MM; c++)
                if (c < nkj || c == ij) {
                    const float vv = g_acc[j-2][b][c];
                    gramS[ij][c] = vv; gramS[c][ij] = vv;
                }
        }
        float* H = Hs;
        for (int i = 0; i < 42; i++) H[i] = 0.f;
        for (int j = 0; j < nk; j++) { H[1+j] = 1.f; H[(1+j)*7] = 1.f; }
#pragma unroll
        for (int i = 0; i < MM; i++) H[(1+i)*7 + (1+i)] = LAMV;
        for (int i = 0; i < nk; i++)
            for (int j = 0; j < nk; j++)
                H[(1+i)*7 + (1+j)] = gramS[i][j] + (i == j ? LAMV : 0.f);
        H[6] = 1.f;
        for (int col = 0; col < 6; col++) {
            int p = col; float mx = fabsf(H[col*7+col]);
            for (int r2 = col+1; r2 < 6; r2++) {
                const float vv = fabsf(H[r2*7+col]);
                if (vv > mx) { mx = vv; p = r2; }
            }
            if (p != col)
                for (int j = col; j < 7; j++) { const float tt = H[col*7+j]; H[col*7+j] = H[p*7+j]; H[p*7+j] = tt; }
            const float piv = H[col*7+col];
            for (int r2 = col+1; r2 < 6; r2++) {
                const float fct = H[r2*7+col] / piv;
                for (int j = col+1; j < 7; j++) H[r2*7+j] -= fct * H[col*7+j];
            }
        }
        for (int r2 = 5; r2 >= 0; r2--) {
            float s = H[r2*7+6];
            for (int j = r2+1; j < 6; j++) s -= H[r2*7+j] * H[j*7+6];
            H[r2*7+6] = s / H[r2*7+r2];
        }
#pragma unroll
        for (int m = 0; m < MM; m++) alphaS[m] = H[(1+m)*7+6];
    }
    __syncthreads();

    float al[MM];
#pragma unroll
    for (int m = 0; m < MM; m++) al[m] = alphaS[m];

    if (nk == MM) {
#pragma unroll
        for (int i = 0; i < 4; i++) {
            const int e = (i*TPB + tid) * 8;
            const int off = base + e;
            float s[8] = {0,0,0,0,0,0,0,0};
#pragma unroll
            for (int m = 0; m < MM; m++) {
                const short8 fm = *(const short8*)(&g_Fm[m][off]);
#pragma unroll
                for (int j = 0; j < 8; j++)
                    s[j] = fmaf(al[m], bf2f((unsigned short)fm[j]), s[j]);
            }
            short8 v;
#pragma unroll
            for (int j = 0; j < 8; j++) v[j] = (short)f2bf(s[j]);
            *(short8*)(As + (e>>9)*PADW + (e&511)) = v;
            *(short8*)(&g_xb[off]) = v;
        }
    } else {
#pragma unroll
        for (int i = 0; i < 4; i++) {
            const int e = (i*TPB + tid) * 8;
            const int off = base + e;
            float s[8] = {0,0,0,0,0,0,0,0};
            for (int m = 0; m < nk; m++) {
                const short8 fm = *(const short8*)(&g_Fm[m][off]);
#pragma unroll
                for (int j = 0; j < 8; j++)
                    s[j] = fmaf(al[m], bf2f((unsigned short)fm[j]), s[j]);
            }
            short8 v;
#pragma unroll
            for (int j = 0; j < 8; j++) v[j] = (short)f2bf(s[j]);
            *(short8*)(As + (e>>9)*PADW + (e&511)) = v;
            *(short8*)(&g_xb[off]) = v;
        }
    }
    __syncthreads();
    mfma_gemm<0>(g_Wb, lin_b, As, Fs, nullptr);
    __syncthreads();
    float dv[6] = {0,0,0,0,0,0};
    float dself = 0.f;
#pragma unroll
    for (int i = 0; i < 4; i++) {
        const int e = (i*TPB + tid) * 8;
        const int off = base + e, lo = (e>>9)*PADW + (e&511);
        const short8 fv = *(const short8*)(Fs + lo);
        const short8 xv = *(const short8*)(As + lo);
        float gg[8]; short8 gv;
#pragma unroll
        for (int j = 0; j < 8; j++) {
            const float ff = bf2f((unsigned short)fv[j]);
            const float g  = ff - bf2f((unsigned short)xv[j]);
            gg[j] = g; gv[j] = (short)f2bf(g);
            dv[5] = fmaf(ff, ff, dv[5]);
            dself = fmaf(g, g, dself);
        }
        *(short8*)(&g_Fm[idx][off]) = fv;
        *(short8*)(&g_G [idx][off]) = gv;
#pragma unroll
        for (int js = 0; js < MM; js++) {
            if (js != idx && js < nk) {
                const short8 gj = *(const short8*)(&g_G[js][off]);
#pragma unroll
                for (int j = 0; j < 8; j++)
                    dv[js] = fmaf(gg[j], bf2f((unsigned short)gj[j]), dv[js]);
            }
        }
    }
    float vals[6];
#pragma unroll
    for (int j = 0; j < MM; j++) vals[j] = (j == idx) ? (dv[j] + dself) : dv[j];
    vals[5] = dv[5];
    red6(vals, redS, &g_acc[it][b][0]);
}

__global__ void __launch_bounds__(TPB, 4) k_final(const float* __restrict__ bias,
                                                  float* __restrict__ out)
{
    __shared__ __align__(16) unsigned short As[ROWS*PADW];
    const int tid = threadIdx.x;
    const int base = blockIdx.x * (ROWS*FD);
#pragma unroll
    for (int i = 0; i < 4; i++) {
        const int e = (i*TPB + tid) * 8;
        *(short8*)(As + (e>>9)*PADW + (e&511)) = *(const short8*)(&g_xb[base + e]);
    }
    __syncthreads();
    mfma_gemm<1>(g_WbO, bias, As, nullptr, out + base);
}

extern "C" void kernel_launch(void* const* d_in, const int* in_sizes, int n_in,
                              void* d_out, int out_size, void* d_ws, size_t ws_size,
                              hipStream_t stream)
{
    (void)in_sizes; (void)n_in; (void)out_size; (void)d_ws; (void)ws_size;
    const float* x      = (const float*)d_in[0];
    const float* lin_w  = (const float*)d_in[1];
    const float* lin_b  = (const float*)d_in[2];
    const float* weight = (const float*)d_in[3];
    const float* bias   = (const float*)d_in[4];
    float* out = (float*)d_out;

    void* args[] = {(void*)&x, (void*)&lin_w, (void*)&lin_b,
                    (void*)&weight, (void*)&bias, (void*)&out};
    if (hipLaunchCooperativeKernel(reinterpret_cast<const void*>(&k_anderson),
                                   dim3(NBLK), dim3(TPB), args, 0, stream) != hipSuccess) {
        // fallback: proven multi-launch path
        hipLaunchKernelGGL(k_init0, dim3(512),  dim3(256), 0, stream, lin_w, weight);
        hipLaunchKernelGGL(k_init1, dim3(NBLK), dim3(TPB), 0, stream, x, lin_b);
        for (int k = 2; k < MAXIT; k++)
            hipLaunchKernelGGL(k_iter, dim3(NBLK), dim3(TPB), 0, stream, lin_b, k);
        hipLaunchKernelGGL(k_final, dim3(NBLK), dim3(TPB), 0, stream, bias, out);
    }
}

// Round 2
// 815.949 us; speedup vs baseline: 1.2894x; 1.2894x over previous
//
#include <hip/hip_runtime.h>
#include <math.h>

#define FD     512
#define NBATCH 16
#define NROWS  16384
#define ROWS   64              // rows per block
#define NBLK   (NROWS/ROWS)    // 256 blocks = 1 per CU (cooperative-resident)
#define TPB    1024            // 16 waves/block
#define MM     5
#define LAMV   1e-4f
#define MAXIT  50
#define TOLV   0.01f
#define NTOT   8388608
#define PADW   520             // LDS row stride (bf16 elems), 16B aligned

typedef __attribute__((ext_vector_type(8))) short  short8;   // 8 bf16
typedef __attribute__((ext_vector_type(4))) float  float4v;  // MFMA C/D frag

// Persistent device state; fully rewritten (or provably unused) every call.
__device__ unsigned short g_Fm[MM][NTOT];
__device__ unsigned short g_G [MM][NTOT];
__device__ unsigned short g_xb[NTOT];          // fallback path only
__device__ unsigned short g_Wb [FD*FD];        // bf16(lin_w) row-major
__device__ unsigned short g_WbO[FD*FD];        // bf16(weight) row-major
__device__ float g_acc [MAXIT-2][NBATCH][8];   // per-iter Gram-row dots [0..4], ||f||^2 [5]
__device__ float g_acc0[NBATCH][8];            // init dots d00,d01,d11
// Fence-free barrier state: MONOTONIC counters, never reset (g_done carries the
// completed-barrier base across launches; launches are stream-ordered).
__device__ unsigned g_leaf[NBATCH];            // +16 per barrier (16 blocks/batch)
__device__ unsigned g_root;                    // +16 per barrier (one per leaf)
__device__ unsigned g_done;                    // barriers completed, all launches

static __device__ __forceinline__ unsigned short f2bf(float f) {
    unsigned u = __float_as_uint(f);
    u += 0x7fff + ((u >> 16) & 1);             // RNE
    return (unsigned short)(u >> 16);
}
static __device__ __forceinline__ float bf2f(unsigned short s) {
    return __uint_as_float(((unsigned)s) << 16);
}

// Agent-scope (device-coherent) atomic helpers: these bypass the non-coherent
// L1/L2 path for the tiny cross-block data, so NO grid-wide cache
// writeback/invalidate is ever needed (that flush was grid.sync()'s ~50us/iter
// cost: it evicted the 33 MB/iter of block-PRIVATE g_Fm/g_G dirty lines).
static __device__ __forceinline__ float aload(const float* p) {
    return __hip_atomic_load(p, __ATOMIC_RELAXED, __HIP_MEMORY_SCOPE_AGENT);
}
static __device__ __forceinline__ void astoref(float* p, float v) {
    __hip_atomic_store(p, v, __ATOMIC_RELAXED, __HIP_MEMORY_SCOPE_AGENT);
}
static __device__ __forceinline__ void astoreu(unsigned* p, unsigned v) {
    __hip_atomic_store(p, v, __ATOMIC_RELAXED, __HIP_MEMORY_SCOPE_AGENT);
}

// 64x512 tile GEMM: D = A(64x512 bf16, LDS) @ W^T + bias.
// A[m=lane&15][k=quad*8+j], B[k=quad*8+j][n=lane&15], C/D col=lane&15,
// row=quad*4+reg (verified m89/m91 layouts).
// MODE 0: bf16 -> FsOut (LDS). MODE 1: fp32 -> gout (global tile base).
template<int MODE>
static __device__ __forceinline__ void mfma_gemm(const unsigned short* __restrict__ Wb,
                                                 const float* __restrict__ bvec,
                                                 const unsigned short* AsIn,
                                                 unsigned short* FsOut,
                                                 float* __restrict__ gout)
{
    const int lane = threadIdx.x & 63;
    const int wv   = threadIdx.x >> 6;     // 0..15
    const int lm   = lane & 15;
    const int quad = lane >> 4;
    float4v acc[4][2];
#pragma unroll
    for (int ct = 0; ct < 2; ct++) {
        const float b = bvec[wv*32 + ct*16 + lm];
#pragma unroll
        for (int r16 = 0; r16 < 4; r16++) {
            acc[r16][ct][0]=b; acc[r16][ct][1]=b; acc[r16][ct][2]=b; acc[r16][ct][3]=b;
        }
    }
#pragma unroll
    for (int q = 0; q < 4; q++) {
#pragma unroll
        for (int kb = 0; kb < 4; kb++) {
            const int ko = q*128 + kb*32 + quad*8;
            short8 bf[2];
#pragma unroll
            for (int ct = 0; ct < 2; ct++)
                bf[ct] = *(const short8*)(Wb + (wv*32 + ct*16 + lm)*FD + ko);
            short8 af[4];
#pragma unroll
            for (int r16 = 0; r16 < 4; r16++)
                af[r16] = *(const short8*)(AsIn + (r16*16 + lm)*PADW + ko);
#pragma unroll
            for (int r16 = 0; r16 < 4; r16++) {
                acc[r16][0] = __builtin_amdgcn_mfma_f32_16x16x32_bf16(af[r16], bf[0], acc[r16][0], 0,0,0);
                acc[r16][1] = __builtin_amdgcn_mfma_f32_16x16x32_bf16(af[r16], bf[1], acc[r16][1], 0,0,0);
            }
        }
    }
#pragma unroll
    for (int ct = 0; ct < 2; ct++) {
        const int c = wv*32 + ct*16 + lm;
#pragma unroll
        for (int r16 = 0; r16 < 4; r16++)
#pragma unroll
            for (int r = 0; r < 4; r++) {
                const int row = r16*16 + quad*4 + r;
                if (MODE == 0) FsOut[row*PADW + c] = f2bf(acc[r16][ct][r]);
                else           gout[row*FD + c]    = acc[r16][ct][r];
            }
    }
}

static __device__ __forceinline__ void red6(const float vals[6], float (*redS)[8], float* accrow)
{
    const int lane = threadIdx.x & 63, wv = threadIdx.x >> 6;   // wv 0..15
#pragma unroll
    for (int j = 0; j < 6; j++) {
        float v = vals[j];
#pragma unroll
        for (int o = 32; o; o >>= 1) v += __shfl_down(v, o);
        if (lane == 0) redS[wv][j] = v;
    }
    __syncthreads();
    if (threadIdx.x < 6) {
        float s = 0.f;
#pragma unroll
        for (int w = 0; w < 16; w++) s += redS[w][threadIdx.x];
        atomicAdd(accrow + threadIdx.x, s);   // device-scope
    }
}

// Fence-free device barrier. Ordering: __syncthreads() drains each wave's vmem
// (s_waitcnt vmcnt(0) before s_barrier), so every block's atomicAdds are
// complete before its leaf arrival; root inc is data-dependent on leaf count.
// No cache maintenance -> block-private L2 lines survive.
#define GBAR() do {                                                                       \
    __syncthreads();                                                                      \
    if (tid == 0) {                                                                       \
        ++nbar;                                                                           \
        const unsigned t16 = (bar_base + (unsigned)nbar) * 16u;                           \
        const unsigned lv = __hip_atomic_fetch_add(&g_leaf[b], 1u,                        \
                              __ATOMIC_RELAXED, __HIP_MEMORY_SCOPE_AGENT) + 1u;           \
        if (lv == t16)                                                                    \
            __hip_atomic_fetch_add(&g_root, 1u,                                           \
                              __ATOMIC_RELAXED, __HIP_MEMORY_SCOPE_AGENT);                \
        while ((int)(__hip_atomic_load(&g_root, __ATOMIC_RELAXED,                         \
                              __HIP_MEMORY_SCOPE_AGENT) - t16) < 0)                       \
            __builtin_amdgcn_s_sleep(2);                                                  \
    }                                                                                     \
    __syncthreads();                                                                      \
} while (0)

// ======================= persistent cooperative kernel =======================
__global__ void __launch_bounds__(TPB, 4) k_anderson(
    const float* __restrict__ x,     const float* __restrict__ lin_w,
    const float* __restrict__ lin_b, const float* __restrict__ weight,
    const float* __restrict__ bias,  float* __restrict__ out)
{
    __shared__ __align__(16) unsigned short As[ROWS*PADW];
    __shared__ __align__(16) unsigned short Fs[ROWS*PADW];
    __shared__ float redS[16][8];
    __shared__ float gramS[MM][MM];
    __shared__ float alphaS[MM];
    __shared__ float Hs[48];
    __shared__ float gAs[MM][MM];   // Gram window cache (wave-1 parallel load)
    __shared__ float ga0S[3];       // d00,d01,d11
    __shared__ float sres;

    const int tid  = threadIdx.x;
    const int t    = blockIdx.x, b = t >> 4;
    const int base = t * (ROWS*FD);

    unsigned bar_base = 0; int nbar = 0;
    if (tid == 0)
        bar_base = __hip_atomic_load(&g_done, __ATOMIC_RELAXED, __HIP_MEMORY_SCOPE_AGENT);

    // ---------- phase 0: weights -> bf16 (coherent stores), zero accs, x->As --
    if (tid < 512) {                            // 256 blk x 512 thr = FD*FD/2 uints
        const int wi = t*512 + tid;
        const float2 w0 = *(const float2*)(lin_w  + 2*wi);
        const float2 w1 = *(const float2*)(weight + 2*wi);
        const unsigned p0 = (unsigned)f2bf(w0.x) | ((unsigned)f2bf(w0.y) << 16);
        const unsigned p1 = (unsigned)f2bf(w1.x) | ((unsigned)f2bf(w1.y) << 16);
        astoreu((unsigned*)g_Wb  + wi, p0);
        astoreu((unsigned*)g_WbO + wi, p1);
    } else {
        const int zi = t*512 + (tid - 512);
        if (zi < (MAXIT-2)*NBATCH*8)            astoref(&g_acc[0][0][0] + zi, 0.f);
        else if (zi < (MAXIT-2)*NBATCH*8 + NBATCH*8)
            astoref(&g_acc0[0][0] + (zi - (MAXIT-2)*NBATCH*8), 0.f);
    }
#pragma unroll
    for (int i = 0; i < 4; i++) {               // bf16(x0 tile) -> As
        const int e = (i*TPB + tid) * 8;
        const float4 a0 = *(const float4*)(x + base + e);
        const float4 a1 = *(const float4*)(x + base + e + 4);
        short8 v;
        v[0]=f2bf(a0.x); v[1]=f2bf(a0.y); v[2]=f2bf(a0.z); v[3]=f2bf(a0.w);
        v[4]=f2bf(a1.x); v[5]=f2bf(a1.y); v[6]=f2bf(a1.z); v[7]=f2bf(a1.w);
        *(short8*)(As + (e>>9)*PADW + (e&511)) = v;
    }
    GBAR();                                     // barrier 1: g_Wb/g_acc-zero ready

    // ---------- init: F0=f(x~0), F1=f(F~0), G0, G1, init Gram dots ------------
    mfma_gemm<0>(g_Wb, lin_b, As, Fs, nullptr);   // Fs = bf16(f(x~0))
    __syncthreads();
    float d00 = 0.f;
#pragma unroll
    for (int i = 0; i < 4; i++) {
        const int e = (i*TPB + tid) * 8;
        const int off = base + e, lo = (e>>9)*PADW + (e&511);
        const short8 fv = *(const short8*)(Fs + lo);
        const short8 xv = *(const short8*)(As + lo);
        short8 gv;
#pragma unroll
        for (int j = 0; j < 8; j++) {
            const float g = bf2f((unsigned short)fv[j]) - bf2f((unsigned short)xv[j]);
            gv[j] = (short)f2bf(g);
            d00 = fmaf(g, g, d00);
        }
        *(short8*)(&g_Fm[0][off]) = fv;
        *(short8*)(&g_G [0][off]) = gv;
    }
    __syncthreads();
    mfma_gemm<0>(g_Wb, lin_b, Fs, As, nullptr);   // As = bf16(f(F~0)) = F1
    __syncthreads();
    float d01 = 0.f, d11 = 0.f;
#pragma unroll
    for (int i = 0; i < 4; i++) {
        const int e = (i*TPB + tid) * 8;
        const int off = base + e, lo = (e>>9)*PADW + (e&511);
        const short8 f1 = *(const short8*)(As + lo);
        const short8 f0 = *(const short8*)(Fs + lo);
        const short8 g0 = *(const short8*)(&g_G[0][off]);
        short8 gv;
#pragma unroll
        for (int j = 0; j < 8; j++) {
            const float g = bf2f((unsigned short)f1[j]) - bf2f((unsigned short)f0[j]);
            gv[j] = (short)f2bf(g);
            d11 = fmaf(g, g, d11);
            d01 = fmaf(bf2f((unsigned short)g0[j]), g, d01);
        }
        *(short8*)(&g_Fm[1][off]) = f1;
        *(short8*)(&g_G [1][off]) = gv;
    }
    {
        const float vals[6] = {d00, d01, d11, 0.f, 0.f, 0.f};
        red6(vals, redS, &g_acc0[b][0]);
    }
    GBAR();                                     // barrier 2: init dots ready

    // ---------------- Anderson iterations (k = 2..49) -------------------------
    for (int k = 2; k < MAXIT; k++) {
        const int it = k - 2, idx = k % MM, nk = (k < MM) ? k : MM;
        const int j0 = (k - 5 > 2) ? (k - 5) : 2;

        // wave 0: residual of iteration k-1 (coherent loads)
        if (k > 2 && (tid >> 6) == 0) {
            float v = 0.f;
            if (tid < 32) {
                const int bb = tid & 15;
                const int jj = (tid < 16) ? ((k-1) % MM) : 5;
                v = aload(&g_acc[it-1][bb][jj]);
            }
            v += __shfl_xor(v, 1); v += __shfl_xor(v, 2);
            v += __shfl_xor(v, 4); v += __shfl_xor(v, 8);
            const float num = __shfl(v, 0), den = __shfl(v, 16);
            if (tid == 0) sres = sqrtf(num) / (1e-5f + sqrtf(den));
        }
        // wave 1: Gram window + init dots -> LDS (coherent loads)
        if ((tid >> 6) == 1) {
            const int l = tid & 63;
            if (l < 25) {
                const int jj = j0 + l/5;
                if (jj < k) gAs[l/5][l%5] = aload(&g_acc[jj-2][b][l%5]);
            } else if (l < 28) {
                ga0S[l-25] = aload(&g_acc0[b][l-25]);
            }
        }
        __syncthreads();
        if (k > 2 && sres < TOLV) break;        // uniform across grid

        // --- Gram replay (chronological, last <=5 iterations) + bordered solve
        if (tid == 0) {
#pragma unroll
            for (int i = 0; i < MM; i++)
#pragma unroll
                for (int j = 0; j < MM; j++) gramS[i][j] = 0.f;
            gramS[0][0] = ga0S[0];
            gramS[0][1] = gramS[1][0] = ga0S[1];
            gramS[1][1] = ga0S[2];
            for (int j = j0; j < k; j++) {
                const int ij = j % MM, nkj = (j < MM) ? j : MM;
                for (int c = 0; c < MM; c++)
                    if (c < nkj || c == ij) {
                        const float vv = gAs[j - j0][c];
                        gramS[ij][c] = vv; gramS[c][ij] = vv;
                    }
            }
            float* H = Hs;                      // 6x7 augmented
            for (int i = 0; i < 42; i++) H[i] = 0.f;
            for (int j = 0; j < nk; j++) { H[1+j] = 1.f; H[(1+j)*7] = 1.f; }
#pragma unroll
            for (int i = 0; i < MM; i++) H[(1+i)*7 + (1+i)] = LAMV;
            for (int i = 0; i < nk; i++)
                for (int j = 0; j < nk; j++)
                    H[(1+i)*7 + (1+j)] = gramS[i][j] + (i == j ? LAMV : 0.f);
            H[6] = 1.f;                         // rhs = e0
            for (int col = 0; col < 6; col++) {
                int p = col; float mx = fabsf(H[col*7+col]);
                for (int r2 = col+1; r2 < 6; r2++) {
                    const float vv = fabsf(H[r2*7+col]);
                    if (vv > mx) { mx = vv; p = r2; }
                }
                if (p != col)
                    for (int j = col; j < 7; j++) { const float tt = H[col*7+j]; H[col*7+j] = H[p*7+j]; H[p*7+j] = tt; }
                const float piv = H[col*7+col];
                for (int r2 = col+1; r2 < 6; r2++) {
                    const float fct = H[r2*7+col] / piv;
                    for (int j = col+1; j < 7; j++) H[r2*7+j] -= fct * H[col*7+j];
                }
            }
            for (int r2 = 5; r2 >= 0; r2--) {
                float s = H[r2*7+6];
                for (int j = r2+1; j < 6; j++) s -= H[r2*7+j] * H[j*7+6];
                H[r2*7+6] = s / H[r2*7+r2];
            }
#pragma unroll
            for (int m = 0; m < MM; m++) alphaS[m] = H[(1+m)*7+6];
        }
        __syncthreads();

        float al[MM];
#pragma unroll
        for (int m = 0; m < MM; m++) al[m] = alphaS[m];

        // --- pass 1: x~ = bf16(sum_m alpha_m Fm[m]) -> As
        // LDS reuse: Fs still holds g_Fm[(k-1)%MM] bit-exactly (pass 2 of k-1);
        // at k=2, As holds g_Fm[1] (init) and Fs holds g_Fm[0].
        {
            const int sF = (k == 2) ? 0 : ((k - 1) % MM);
            const int sA = (k == 2) ? 1 : -1;
#pragma unroll
            for (int i = 0; i < 4; i++) {
                const int e = (i*TPB + tid) * 8;
                const int off = base + e, lo = (e>>9)*PADW + (e&511);
                float s[8] = {0,0,0,0,0,0,0,0};
                for (int m = 0; m < nk; m++) {
                    short8 fm;
                    if (m == sF)      fm = *(const short8*)(Fs + lo);
                    else if (m == sA) fm = *(const short8*)(As + lo);
                    else              fm = *(const short8*)(&g_Fm[m][off]);
#pragma unroll
                    for (int j = 0; j < 8; j++)
                        s[j] = fmaf(al[m], bf2f((unsigned short)fm[j]), s[j]);
                }
                short8 v;
#pragma unroll
                for (int j = 0; j < 8; j++) v[j] = (short)f2bf(s[j]);
                *(short8*)(As + (e>>9)*PADW + (e&511)) = v;
            }
        }
        __syncthreads();
        // --- pass 2: Fs = bf16(x~ @ lin_w^T + lin_b)
        mfma_gemm<0>(g_Wb, lin_b, As, Fs, nullptr);
        __syncthreads();
        // --- pass 3: state writes + Gram-row dots + residual partials
        float dv[6] = {0,0,0,0,0,0};
        float dself = 0.f;
#pragma unroll
        for (int i = 0; i < 4; i++) {
            const int e = (i*TPB + tid) * 8;
            const int off = base + e, lo = (e>>9)*PADW + (e&511);
            const short8 fv = *(const short8*)(Fs + lo);
            const short8 xv = *(const short8*)(As + lo);
            float gg[8]; short8 gv;
#pragma unroll
            for (int j = 0; j < 8; j++) {
                const float ff = bf2f((unsigned short)fv[j]);
                const float g  = ff - bf2f((unsigned short)xv[j]);
                gg[j] = g; gv[j] = (short)f2bf(g);
                dv[5] = fmaf(ff, ff, dv[5]);
                dself = fmaf(g, g, dself);
            }
            *(short8*)(&g_Fm[idx][off]) = fv;
            *(short8*)(&g_G [idx][off]) = gv;
#pragma unroll
            for (int js = 0; js < MM; js++) {
                if (js != idx && js < nk) {
                    const short8 gj = *(const short8*)(&g_G[js][off]);
#pragma unroll
                    for (int j = 0; j < 8; j++)
                        dv[js] = fmaf(gg[j], bf2f((unsigned short)gj[j]), dv[js]);
                }
            }
        }
        float vals[6];
#pragma unroll
        for (int j = 0; j < MM; j++) vals[j] = (j == idx) ? (dv[j] + dself) : dv[j];
        vals[5] = dv[5];
        red6(vals, redS, &g_acc[it][b][0]);
        GBAR();                                 // g_acc[it] ready device-wide
    }

    // ---------------- final: out = x~last @ weight^T + bias (fp32) -----------
    // As (LDS) still holds bf16(xnew) of the last executed iteration.
    mfma_gemm<1>(g_WbO, bias, As, nullptr, out + base);

    if (t == 0 && tid == 0)
        astoreu(&g_done, bar_base + (unsigned)nbar);   // next launch's barrier base
}

// ===================== fallback multi-launch path (proven) ===================
__global__ void __launch_bounds__(256) k_init0(const float* __restrict__ lin_w,
                                               const float* __restrict__ weight)
{
    const int i0 = blockIdx.x*256 + threadIdx.x, stride = gridDim.x*256;
    for (int i = i0; i < FD*FD; i += stride) {
        g_Wb [i] = f2bf(lin_w[i]);
        g_WbO[i] = f2bf(weight[i]);
    }
    float* a = &g_acc[0][0][0];
    for (int i = i0; i < (MAXIT-2)*NBATCH*8; i += stride) a[i] = 0.f;
    float* a0 = &g_acc0[0][0];
    for (int i = i0; i < NBATCH*8; i += stride) a0[i] = 0.f;
}

__global__ void __launch_bounds__(TPB, 4) k_init1(const float* __restrict__ x,
                                                  const float* __restrict__ lin_b)
{
    __shared__ __align__(16) unsigned short As[ROWS*PADW];
    __shared__ __align__(16) unsigned short Fs[ROWS*PADW];
    __shared__ float redS[16][8];
    const int tid = threadIdx.x;
    const int t = blockIdx.x, b = t >> 4;
    const int base = t * (ROWS*FD);

#pragma unroll
    for (int i = 0; i < 4; i++) {
        const int e = (i*TPB + tid) * 8;
        const float4 a0 = *(const float4*)(x + base + e);
        const float4 a1 = *(const float4*)(x + base + e + 4);
        short8 v;
        v[0]=f2bf(a0.x); v[1]=f2bf(a0.y); v[2]=f2bf(a0.z); v[3]=f2bf(a0.w);
        v[4]=f2bf(a1.x); v[5]=f2bf(a1.y); v[6]=f2bf(a1.z); v[7]=f2bf(a1.w);
        *(short8*)(As + (e>>9)*PADW + (e&511)) = v;
    }
    __syncthreads();
    mfma_gemm<0>(g_Wb, lin_b, As, Fs, nullptr);
    __syncthreads();
    float d00 = 0.f;
#pragma unroll
    for (int i = 0; i < 4; i++) {
        const int e = (i*TPB + tid) * 8;
        const int off = base + e, lo = (e>>9)*PADW + (e&511);
        const short8 fv = *(const short8*)(Fs + lo);
        const short8 xv = *(const short8*)(As + lo);
        short8 gv;
#pragma unroll
        for (int j = 0; j < 8; j++) {
            const float g = bf2f((unsigned short)fv[j]) - bf2f((unsigned short)xv[j]);
            gv[j] = (short)f2bf(g);
            d00 = fmaf(g, g, d00);
        }
        *(short8*)(&g_Fm[0][off]) = fv;
        *(short8*)(&g_G [0][off]) = gv;
    }
    __syncthreads();
    mfma_gemm<0>(g_Wb, lin_b, Fs, As, nullptr);
    __syncthreads();
    float d01 = 0.f, d11 = 0.f;
#pragma unroll
    for (int i = 0; i < 4; i++) {
        const int e = (i*TPB + tid) * 8;
        const int off = base + e, lo = (e>>9)*PADW + (e&511);
        const short8 f1 = *(const short8*)(As + lo);
        const short8 f0 = *(const short8*)(Fs + lo);
        const short8 g0 = *(const short8*)(&g_G[0][off]);
        short8 gv;
#pragma unroll
        for (int j = 0; j < 8; j++) {
            const float g = bf2f((unsigned short)f1[j]) - bf2f((unsigned short)f0[j]);
            gv[j] = (short)f2bf(g);
            d11 = fmaf(g, g, d11);
            d01 = fmaf(bf2f((unsigned short)g0[j]), g, d01);
        }
        *(short8*)(&g_Fm[1][off]) = f1;
        *(short8*)(&g_G [1][off]) = gv;
    }
    const float vals[6] = {d00, d01, d11, 0.f, 0.f, 0.f};
    red6(vals, redS, &g_acc0[b][0]);
}

__global__ void __launch_bounds__(TPB, 4) k_iter(const float* __restrict__ lin_b, int k)
{
    __shared__ __align__(16) unsigned short As[ROWS*PADW];
    __shared__ __align__(16) unsigned short Fs[ROWS*PADW];
    __shared__ float gramS[MM][MM];
    __shared__ float alphaS[MM];
    __shared__ float Hs[48];
    __shared__ float redS[16][8];
    __shared__ float sres;

    const int tid = threadIdx.x;
    const int t = blockIdx.x, b = t >> 4;
    const int base = t * (ROWS*FD);
    const int it = k - 2, idx = k % MM, nk = (k < MM) ? k : MM;

    if (k > 2) {
        float v = 0.f;
        if (tid < 32) {
            const int bb = tid & 15;
            const int jj = (tid < 16) ? ((k-1) % MM) : 5;
            v = g_acc[it-1][bb][jj];
        }
        v += __shfl_xor(v, 1); v += __shfl_xor(v, 2);
        v += __shfl_xor(v, 4); v += __shfl_xor(v, 8);
        const float num = __shfl(v, 0), den = __shfl(v, 16);
        if (tid == 0) sres = sqrtf(num) / (1e-5f + sqrtf(den));
    }
    __syncthreads();
    if (k > 2 && sres < TOLV) return;

    if (tid == 0) {
#pragma unroll
        for (int i = 0; i < MM; i++)
#pragma unroll
            for (int j = 0; j < MM; j++) gramS[i][j] = 0.f;
        gramS[0][0] = g_acc0[b][0];
        gramS[0][1] = gramS[1][0] = g_acc0[b][1];
        gramS[1][1] = g_acc0[b][2];
        const int j0 = (k - 5 > 2) ? (k - 5) : 2;
        for (int j = j0; j < k; j++) {
            const int ij = j % MM, nkj = (j < MM) ? j : MM;
            for (int c = 0; c < MM; c++)
                if (c < nkj || c == ij) {
                    const float vv = g_acc[j-2][b][c];
                    gramS[ij][c] = vv; gramS[c][ij] = vv;
                }
        }
        float* H = Hs;
        for (int i = 0; i < 42; i++) H[i] = 0.f;
        for (int j = 0; j < nk; j++) { H[1+j] = 1.f; H[(1+j)*7] = 1.f; }
#pragma unroll
        for (int i = 0; i < MM; i++) H[(1+i)*7 + (1+i)] = LAMV;
        for (int i = 0; i < nk; i++)
            for (int j = 0; j < nk; j++)
                H[(1+i)*7 + (1+j)] = gramS[i][j] + (i == j ? LAMV : 0.f);
        H[6] = 1.f;
        for (int col = 0; col < 6; col++) {
            int p = col; float mx = fabsf(H[col*7+col]);
            for (int r2 = col+1; r2 < 6; r2++) {
                const float vv = fabsf(H[r2*7+col]);
                if (vv > mx) { mx = vv; p = r2; }
            }
            if (p != col)
                for (int j = col; j < 7; j++) { const float tt = H[col*7+j]; H[col*7+j] = H[p*7+j]; H[p*7+j] = tt; }
            const float piv = H[col*7+col];
            for (int r2 = col+1; r2 < 6; r2++) {
                const float fct = H[r2*7+col] / piv;
                for (int j = col+1; j < 7; j++) H[r2*7+j] -= fct * H[col*7+j];
            }
        }
        for (int r2 = 5; r2 >= 0; r2--) {
            float s = H[r2*7+6];
            for (int j = r2+1; j < 6; j++) s -= H[r2*7+j] * H[j*7+6];
            H[r2*7+6] = s / H[r2*7+r2];
        }
#pragma unroll
        for (int m = 0; m < MM; m++) alphaS[m] = H[(1+m)*7+6];
    }
    __syncthreads();

    float al[MM];
#pragma unroll
    for (int m = 0; m < MM; m++) al[m] = alphaS[m];

    if (nk == MM) {
#pragma unroll
        for (int i = 0; i < 4; i++) {
            const int e = (i*TPB + tid) * 8;
            const int off = base + e;
            float s[8] = {0,0,0,0,0,0,0,0};
#pragma unroll
            for (int m = 0; m < MM; m++) {
                const short8 fm = *(const short8*)(&g_Fm[m][off]);
#pragma unroll
                for (int j = 0; j < 8; j++)
                    s[j] = fmaf(al[m], bf2f((unsigned short)fm[j]), s[j]);
            }
            short8 v;
#pragma unroll
            for (int j = 0; j < 8; j++) v[j] = (short)f2bf(s[j]);
            *(short8*)(As + (e>>9)*PADW + (e&511)) = v;
            *(short8*)(&g_xb[off]) = v;
        }
    } else {
#pragma unroll
        for (int i = 0; i < 4; i++) {
            const int e = (i*TPB + tid) * 8;
            const int off = base + e;
            float s[8] = {0,0,0,0,0,0,0,0};
            for (int m = 0; m < nk; m++) {
                const short8 fm = *(const short8*)(&g_Fm[m][off]);
#pragma unroll
                for (int j = 0; j < 8; j++)
                    s[j] = fmaf(al[m], bf2f((unsigned short)fm[j]), s[j]);
            }
            short8 v;
#pragma unroll
            for (int j = 0; j < 8; j++) v[j] = (short)f2bf(s[j]);
            *(short8*)(As + (e>>9)*PADW + (e&511)) = v;
            *(short8*)(&g_xb[off]) = v;
        }
    }
    __syncthreads();
    mfma_gemm<0>(g_Wb, lin_b, As, Fs, nullptr);
    __syncthreads();
    float dv[6] = {0,0,0,0,0,0};
    float dself = 0.f;
#pragma unroll
    for (int i = 0; i < 4; i++) {
        const int e = (i*TPB + tid) * 8;
        const int off = base + e, lo = (e>>9)*PADW + (e&511);
        const short8 fv = *(const short8*)(Fs + lo);
        const short8 xv = *(const short8*)(As + lo);
        float gg[8]; short8 gv;
#pragma unroll
        for (int j = 0; j < 8; j++) {
            const float ff = bf2f((unsigned short)fv[j]);
            const float g  = ff - bf2f((unsigned short)xv[j]);
            gg[j] = g; gv[j] = (short)f2bf(g);
            dv[5] = fmaf(ff, ff, dv[5]);
            dself = fmaf(g, g, dself);
        }
        *(short8*)(&g_Fm[idx][off]) = fv;
        *(short8*)(&g_G [idx][off]) = gv;
#pragma unroll
        for (int js = 0; js < MM; js++) {
            if (js != idx && js < nk) {
                const short8 gj = *(const short8*)(&g_G[js][off]);
#pragma unroll
                for (int j = 0; j < 8; j++)
                    dv[js] = fmaf(gg[j], bf2f((unsigned short)gj[j]), dv[js]);
            }
        }
    }
    float vals[6];
#pragma unroll
    for (int j = 0; j < MM; j++) vals[j] = (j == idx) ? (dv[j] + dself) : dv[j];
    vals[5] = dv[5];
    red6(vals, redS, &g_acc[it][b][0]);
}

__global__ void __launch_bounds__(TPB, 4) k_final(const float* __restrict__ bias,
                                                  float* __restrict__ out)
{
    __shared__ __align__(16) unsigned short As[ROWS*PADW];
    const int tid = threadIdx.x;
    const int base = blockIdx.x * (ROWS*FD);
#pragma unroll
    for (int i = 0; i < 4; i++) {
        const int e = (i*TPB + tid) * 8;
        *(short8*)(As + (e>>9)*PADW + (e&511)) = *(const short8*)(&g_xb[base + e]);
    }
    __syncthreads();
    mfma_gemm<1>(g_WbO, bias, As, nullptr, out + base);
}

extern "C" void kernel_launch(void* const* d_in, const int* in_sizes, int n_in,
                              void* d_out, int out_size, void* d_ws, size_t ws_size,
                              hipStream_t stream)
{
    (void)in_sizes; (void)n_in; (void)out_size; (void)d_ws; (void)ws_size;
    const float* x      = (const float*)d_in[0];
    const float* lin_w  = (const float*)d_in[1];
    const float* lin_b  = (const float*)d_in[2];
    const float* weight = (const float*)d_in[3];
    const float* bias   = (const float*)d_in[4];
    float* out = (float*)d_out;

    void* args[] = {(void*)&x, (void*)&lin_w, (void*)&lin_b,
                    (void*)&weight, (void*)&bias, (void*)&out};
    if (hipLaunchCooperativeKernel(reinterpret_cast<const void*>(&k_anderson),
                                   dim3(NBLK), dim3(TPB), args, 0, stream) != hipSuccess) {
        // fallback: proven multi-launch path
        hipLaunchKernelGGL(k_init0, dim3(512),  dim3(256), 0, stream, lin_w, weight);
        hipLaunchKernelGGL(k_init1, dim3(NBLK), dim3(TPB), 0, stream, x, lin_b);
        for (int k = 2; k < MAXIT; k++)
            hipLaunchKernelGGL(k_iter, dim3(NBLK), dim3(TPB), 0, stream, lin_b, k);
        hipLaunchKernelGGL(k_final, dim3(NBLK), dim3(TPB), 0, stream, bias, out);
    }
}